// Round 13
// baseline (625.494 us; speedup 1.0000x reference)
//
#include <hip/hip_runtime.h>
#include <hip/hip_bf16.h>
#include <cstdint>

typedef __attribute__((ext_vector_type(4))) float f32x4;
typedef _Float16 f16x8 __attribute__((ext_vector_type(8)));

#define BN_EPS 1e-5f

// ---------------- fp32 -> fp16 cast (only W, 4 MB) ----------------
__global__ __launch_bounds__(256)
void cast_f32_f16(const float* __restrict__ src, _Float16* __restrict__ dst, int n8) {
    int i = blockIdx.x * blockDim.x + threadIdx.x;
    if (i >= n8) return;
    const float4* s4 = (const float4*)src;
    float4 a = s4[2 * (size_t)i];
    float4 b = s4[2 * (size_t)i + 1];
    f16x8 h;
    h[0] = (_Float16)a.x; h[1] = (_Float16)a.y; h[2] = (_Float16)a.z; h[3] = (_Float16)a.w;
    h[4] = (_Float16)b.x; h[5] = (_Float16)b.y; h[6] = (_Float16)b.z; h[7] = (_Float16)b.w;
    *(f16x8*)(dst + 8 * (size_t)i) = h;
}

// async global->LDS, 16B per lane, wave-uniform LDS base
__device__ __forceinline__ void async16(const char* g, char* l) {
    __builtin_amdgcn_global_load_lds(
        (const __attribute__((address_space(1))) unsigned int*)(uintptr_t)g,
        (__attribute__((address_space(3))) unsigned int*)(uintptr_t)l,
        16, 0, 0);
}

// ========== 128x128 tile, BK=32: A fragments DIRECT FROM GLOBAL (no A in LDS) ==========
// Rationale: every fp32-in-LDS layout conflicted (r11/r12: 1.678e7); the only measured-0
// LDS pattern is the f16 [rows][32] B path (r3/r4/r7/r9) — so only B goes through LDS.
// A: lane (fr,kg) loads rows row0+wr*64+m*16+fr, k = kt*32+kg*8..+7 as 2x dwordx4 per m,
// register-pipelined one tile ahead (rA in flight while computing cvt'd regs). cvt's
// compiler-inserted vmcnt (reg dep) retires the OLDER B-staging writes (FIFO); explicit
// vmcnt(2) before each barrier pins B(kt) retirement; B(kt+2) is issued after the loads
// the next cvt waits on, so its prefetch survives. 3-buffer B (24KB) + red 2KB -> 26KB,
// ~150 VGPR -> 3 blocks/CU (12 waves/CU) for latency hiding. No A-cast kernel, no A LDS.

#define BBUF(t) (lds + ((t) % 3) * 8192)

__global__ __launch_bounds__(256)
void gemm_gbn_kernel(const float* __restrict__ Af,
                     const _Float16* __restrict__ Bw,
                     const float* __restrict__ priors,
                     const float* __restrict__ gamma,
                     const float* __restrict__ beta,
                     float* __restrict__ Z,
                     int M, int N, int K)
{
    __shared__ __align__(16) char lds[3 * 8192];      // B: 3 x [128][32] f16
    __shared__ float red[2][128][2];                  // GBN reduction

    const int tid  = threadIdx.x;
    const int lane = tid & 63;
    const int wid  = tid >> 6;     // 0..3
    const int wr   = wid >> 1;     // 0..1 (64-row slice)
    const int wc   = wid & 1;      // 0..1 (64-col slice)
    const int fr   = lane & 15;
    const int kg   = lane >> 4;

    // XCD-aware bijective swizzle (2048 blocks): col-block fastest within an XCD chunk
    // -> the 8 col-blocks of one A row-panel run consecutively on one XCD (L2-shared).
    const int bid = blockIdx.x;
    const int swz = (bid & 7) * 256 + (bid >> 3);
    const int row0 = (swz >> 3) * 128;
    const int col0 = (swz & 7) * 128;

    // B staging source (proven): thread t covers row t>>2 (+64 on 2nd issue), pre-permuted slot
    const int bperm = ((tid & 3) ^ ((tid >> 3) & 3)) * 16;
    const char* b0 = (const char*)Bw + (size_t)(col0 + (tid >> 2)) * (size_t)K * 2 + bperm;
    const char* b1 = b0 + (size_t)64 * K * 2;

    // B fragment read base ([128][32] f16, 64B rows), measured-0-conflict swizzle
    int boff = (wc * 64 + fr) * 64 + kg * 16;
    boff ^= ((boff >> 7) & 3) << 4;

    // A per-lane global base: row = row0 + wr*64 + fr, k-group base kg*8
    const float* aBase = Af + (size_t)(row0 + wr * 64 + fr) * (size_t)K + kg * 8;
    const size_t rowStep = (size_t)16 * K;   // m stride (16 rows)

    f32x4 acc[4][4];
    #pragma unroll
    for (int m = 0; m < 4; ++m)
        #pragma unroll
        for (int n = 0; n < 4; ++n)
            acc[m][n] = (f32x4)0.0f;

    const int nt = K >> 5;   // 64 K-tiles of 32

    // prologue: stage B(0), B(1); then issue A(0) (so cvt's wait retires B first)
    {
        char* d0 = BBUF(0) + wid * 1024;
        async16(b0, d0);  async16(b1, d0 + 4096);
        char* d1 = BBUF(1) + wid * 1024;
        async16(b0 + 64, d1);  async16(b1 + 64, d1 + 4096);
    }
    f32x4 rA[8];
    #pragma unroll
    for (int m = 0; m < 4; ++m) {
        rA[2 * m]     = *(const f32x4*)(aBase + m * rowStep);
        rA[2 * m + 1] = *(const f32x4*)(aBase + m * rowStep + 4);
    }

    for (int kt = 0; kt < nt; ++kt) {
        // cvt current tile's A (compiler vmcnt wait on rA retires older B(kt) writes)
        f16x8 a[4];
        #pragma unroll
        for (int m = 0; m < 4; ++m) {
            f32x4 lo = rA[2 * m], hi = rA[2 * m + 1];
            f16x8 h;
            h[0] = (_Float16)lo[0]; h[1] = (_Float16)lo[1];
            h[2] = (_Float16)lo[2]; h[3] = (_Float16)lo[3];
            h[4] = (_Float16)hi[0]; h[5] = (_Float16)hi[1];
            h[6] = (_Float16)hi[2]; h[7] = (_Float16)hi[3];
            a[m] = h;
        }
        asm volatile("s_waitcnt vmcnt(2)" ::: "memory");   // B(kt) retired; B(kt+1) may fly
        __builtin_amdgcn_s_barrier();                      // all waves' B(kt) visible

        if (kt + 1 < nt) {                                 // issue next tile's A loads
            const float* an = aBase + (size_t)(kt + 1) * 32;
            #pragma unroll
            for (int m = 0; m < 4; ++m) {
                rA[2 * m]     = *(const f32x4*)(an + m * rowStep);
                rA[2 * m + 1] = *(const f32x4*)(an + m * rowStep + 4);
            }
        }

        f16x8 b[4];
        const char* bb = BBUF(kt);
        #pragma unroll
        for (int n = 0; n < 4; ++n) b[n] = *(const f16x8*)(bb + boff + n * 1024);

        __builtin_amdgcn_s_setprio(1);
        #pragma unroll
        for (int m = 0; m < 4; ++m)
            #pragma unroll
            for (int n = 0; n < 4; ++n)
                acc[m][n] = __builtin_amdgcn_mfma_f32_16x16x32_f16(a[m], b[n], acc[m][n], 0, 0, 0);
        __builtin_amdgcn_s_setprio(0);

        if (kt + 2 < nt) {                                 // stage B(kt+2) LAST (prefetch survives)
            char* d = BBUF(kt + 2) + wid * 1024;
            const char* s = b0 + (size_t)(kt + 2) * 64;
            async16(s, d);
            async16(s + (size_t)64 * K * 2, d + 4096);     // note: b1 + off == s + 64*K*2
        }
    }

    // ---- fused Ghost BatchNorm + priors epilogue (block = one 128-row virtual batch) ----
    __syncthreads();
    #pragma unroll
    for (int n = 0; n < 4; ++n) {
        float s1 = 0.f, s2 = 0.f;
        #pragma unroll
        for (int m = 0; m < 4; ++m)
            #pragma unroll
            for (int j = 0; j < 4; ++j) {
                float v = acc[m][n][j];
                s1 += v; s2 += v * v;
            }
        s1 += __shfl_xor(s1, 16); s2 += __shfl_xor(s2, 16);
        s1 += __shfl_xor(s1, 32); s2 += __shfl_xor(s2, 32);
        if (lane < 16) {
            red[wr][wc * 64 + n * 16 + lane][0] = s1;
            red[wr][wc * 64 + n * 16 + lane][1] = s2;
        }
    }
    __syncthreads();

    const int rowb = row0 + wr * 64 + kg * 4;
    #pragma unroll
    for (int n = 0; n < 4; ++n) {
        const int c = wc * 64 + n * 16 + fr;
        float s1 = red[0][c][0] + red[1][c][0];
        float s2 = red[0][c][1] + red[1][c][1];
        float mean = s1 * (1.f / 128.f);
        float var  = s2 * (1.f / 128.f) - mean * mean;
        float rstd = rsqrtf(var + BN_EPS);
        float g = gamma[col0 + c] * rstd;
        float b = beta[col0 + c] - mean * g;
        #pragma unroll
        for (int m = 0; m < 4; ++m)
            #pragma unroll
            for (int j = 0; j < 4; ++j) {
                int r = rowb + m * 16 + j;
                size_t off = (size_t)r * N + col0 + c;
                Z[off] = (acc[m][n][j] * g + b) * priors[off];
            }
    }
}

// ---------------- sparsemax: one wave per row of 1024, exact Michelot projection ----------------
__device__ __forceinline__ float waveSum(float v) {
    #pragma unroll
    for (int off = 32; off > 0; off >>= 1) v += __shfl_xor(v, off);
    return v;
}

__global__ __launch_bounds__(256)
void sparsemax_kernel(float* __restrict__ Z) {
    const int lane = threadIdx.x & 63;
    const int wid  = threadIdx.x >> 6;
    const size_t row = (size_t)blockIdx.x * 4 + wid;
    float4* zr4 = (float4*)(Z + row * 1024);

    float p[16];
    #pragma unroll
    for (int j = 0; j < 4; ++j) {
        float4 t = zr4[lane * 4 + j];
        p[4 * j + 0] = t.x; p[4 * j + 1] = t.y; p[4 * j + 2] = t.z; p[4 * j + 3] = t.w;
    }

    float s = 0.f;
    #pragma unroll
    for (int i = 0; i < 16; ++i) s += p[i];
    s = waveSum(s);

    float kc  = 1024.f;
    float tau = (s - 1.f) * (1.f / 1024.f);
    for (int it = 0; it < 64; ++it) {
        float s2 = 0.f, c2 = 0.f;
        #pragma unroll
        for (int i = 0; i < 16; ++i) {
            if (p[i] > tau) { s2 += p[i]; c2 += 1.f; }
        }
        s2 = waveSum(s2); c2 = waveSum(c2);
        if (c2 == kc) break;        // support stable -> tau exact
        kc = c2;
        tau = (s2 - 1.f) / c2;
    }

    #pragma unroll
    for (int j = 0; j < 4; ++j) {
        float4 o;
        o.x = fmaxf(p[4 * j + 0] - tau, 0.f);
        o.y = fmaxf(p[4 * j + 1] - tau, 0.f);
        o.z = fmaxf(p[4 * j + 2] - tau, 0.f);
        o.w = fmaxf(p[4 * j + 3] - tau, 0.f);
        zr4[lane * 4 + j] = o;
    }
}

extern "C" void kernel_launch(void* const* d_in, const int* in_sizes, int n_in,
                              void* d_out, int out_size, void* d_ws, size_t ws_size,
                              hipStream_t stream)
{
    const float* priors = (const float*)d_in[0];
    const float* feat   = (const float*)d_in[1];
    const float* W      = (const float*)d_in[2];
    const float* gamma  = (const float*)d_in[3];
    const float* beta   = (const float*)d_in[4];
    float* out = (float*)d_out;

    const int Nf = in_sizes[3];              // 1024
    const int Kf = in_sizes[2] / Nf;         // 2048
    const int Mr = in_sizes[1] / Kf;         // 32768

    _Float16* Wh = (_Float16*)d_ws;          // N*K*2 = 4 MB (only W is pre-cast)

    {
        int n8 = Nf * (Kf / 8);
        cast_f32_f16<<<(n8 + 255) / 256, 256, 0, stream>>>(W, Wh, n8);
    }

    int nblk = (Mr / 128) * (Nf / 128);      // 2048, divisible by 8
    gemm_gbn_kernel<<<nblk, 256, 0, stream>>>(feat, Wh, priors, gamma, beta, out, Mr, Nf, Kf);

    sparsemax_kernel<<<Mr / 4, 256, 0, stream>>>(out);
}

// Round 14
// 335.858 us; speedup vs baseline: 1.8624x; 1.8624x over previous
//
#include <hip/hip_runtime.h>
#include <hip/hip_bf16.h>
#include <cstdint>

typedef __attribute__((ext_vector_type(4))) float f32x4;
typedef _Float16 f16x8 __attribute__((ext_vector_type(8)));
typedef _Float16 f16x4 __attribute__((ext_vector_type(4)));

#define BN_EPS 1e-5f

// ---------------- fp32 -> fp16 cast (only W, 4 MB) ----------------
__global__ __launch_bounds__(256)
void cast_f32_f16(const float* __restrict__ src, _Float16* __restrict__ dst, int n8) {
    int i = blockIdx.x * blockDim.x + threadIdx.x;
    if (i >= n8) return;
    const float4* s4 = (const float4*)src;
    float4 a = s4[2 * (size_t)i];
    float4 b = s4[2 * (size_t)i + 1];
    f16x8 h;
    h[0] = (_Float16)a.x; h[1] = (_Float16)a.y; h[2] = (_Float16)a.z; h[3] = (_Float16)a.w;
    h[4] = (_Float16)b.x; h[5] = (_Float16)b.y; h[6] = (_Float16)b.z; h[7] = (_Float16)b.w;
    *(f16x8*)(dst + 8 * (size_t)i) = h;
}

// async global->LDS, 16B per lane, wave-uniform LDS base (B path)
__device__ __forceinline__ void async16(const char* g, char* l) {
    __builtin_amdgcn_global_load_lds(
        (const __attribute__((address_space(1))) unsigned int*)(uintptr_t)g,
        (__attribute__((address_space(3))) unsigned int*)(uintptr_t)l,
        16, 0, 0);
}

// ========= 128x128 tile, BK=32, 3-buffer; A-cast FUSED via coalesced reg->cvt->ds_write =========
// LDS geometry for BOTH operands = the measured-0-conflict f16 [128][32] + XOR swizzle
// (phys 16B-slot = logical ^ ((row>>1)&3)) from r3/r4/r7. B staged via global_load_lds with
// pre-permuted source (proven). A staged fp32->f16 in-kernel:
//   load j (j=0..3): lane l reads 16B fp32 at row (wid*32 + j*8 + (l>>3)), granule (l&7)
//     -> per instruction 8 rows x 8 lanes = 8 FULL 128B lines (coalesced; fixes r13's 16-line split)
//   cvt f32x4 -> f16x4, ds_write_b64 to swizzled dest (bank pattern 2-way = free, m136).
// Pipeline (1 barrier/tile, FIFO vmcnt ledger, per-wave events: A=4 loads, B=2 asyncs):
//   iter kt: (a) cvt+write A(kt+1) [compiler vmcnt(2) retires A(kt+1), leaves B(kt+1)]
//            (b) issue A(kt+2) loads  (c) issue B(kt+2) asyncs
//            (d) ds_read frags(kt)    (e) 16 MFMA
//            (f) vmcnt(6) retires B(kt+1) [outstanding: B(kt+1)2,A(kt+2)4,B(kt+2)2=8]
//            (g) lgkmcnt(0) [ds_writes visible] ; barrier
// Write-after-read: (a)@kt writes abuf[(kt+1)%3], last read @kt-2, retired 2 barriers ago. Safe.
// Tail: kt=nt-2 waits vmcnt(0); kt=nt-1 skips stage+waits.

#define ABUF(t) (lds + ((t) % 3) * 8192)
#define BBUF(t) (lds + 24576 + ((t) % 3) * 8192)

__global__ __launch_bounds__(256)
void gemm_gbn_kernel(const float* __restrict__ Af,
                     const _Float16* __restrict__ Bw,
                     const float* __restrict__ priors,
                     const float* __restrict__ gamma,
                     const float* __restrict__ beta,
                     _Float16* __restrict__ Zh,
                     int M, int N, int K)
{
    __shared__ __align__(16) char lds[6 * 8192];      // A 3x8KB + B 3x8KB
    __shared__ float red[2][128][2];                  // GBN reduction

    const int tid  = threadIdx.x;
    const int lane = tid & 63;
    const int wid  = tid >> 6;     // 0..3
    const int wr   = wid >> 1;     // 0..1 (64-row slice)
    const int wc   = wid & 1;      // 0..1 (64-col slice)
    const int fr   = lane & 15;
    const int kg   = lane >> 4;

    // XCD-aware bijective swizzle (2048 blocks): col-block fastest within an XCD chunk
    const int bid = blockIdx.x;
    const int swz = (bid & 7) * 256 + (bid >> 3);
    const int row0 = (swz >> 3) * 128;
    const int col0 = (swz & 7) * 128;

    // ---- A fused-cast staging setup ----
    // load j: row = wid*32 + j*8 + (lane>>3), fp32 granule (lane&7) (16B)
    const int arow0 = wid * 32 + (lane >> 3);
    const float* aRow[4];
    int wA[4];
    #pragma unroll
    for (int j = 0; j < 4; ++j) {
        const int wrow = arow0 + j * 8;
        aRow[j] = Af + (size_t)(row0 + wrow) * (size_t)K + (lane & 7) * 4;
        const int sub = lane & 7;
        const int x = (wrow >> 1) & 3;
        wA[j] = wrow * 64 + (((sub >> 1) ^ x) * 16) + (sub & 1) * 8;
    }

    // ---- B staging (proven gload_lds path) ----
    const int bperm = ((tid & 3) ^ ((tid >> 3) & 3)) * 16;
    const char* b0 = (const char*)Bw + (size_t)(col0 + (tid >> 2)) * (size_t)K * 2 + bperm;
    const char* b1 = b0 + (size_t)64 * K * 2;

    // ---- fragment read offsets (measured-0-conflict swizzle) ----
    int aoff = (wr * 64 + fr) * 64 + kg * 16;
    aoff ^= ((aoff >> 7) & 3) << 4;
    int boff = (wc * 64 + fr) * 64 + kg * 16;
    boff ^= ((boff >> 7) & 3) << 4;

    f32x4 acc[4][4];
    #pragma unroll
    for (int m = 0; m < 4; ++m)
        #pragma unroll
        for (int n = 0; n < 4; ++n)
            acc[m][n] = (f32x4)0.0f;

    const int nt = K >> 5;   // 64 K-tiles of 32
    f32x4 rA[4];

    // ---- prologue ----
    #pragma unroll
    for (int j = 0; j < 4; ++j) rA[j] = *(const f32x4*)(aRow[j]);           // A(0)
    { char* d = BBUF(0) + wid * 1024; async16(b0, d); async16(b1, d + 4096); }  // B(0)
    #pragma unroll
    for (int j = 0; j < 4; ++j) {                                            // cvt+write A(0)
        f16x4 h;
        h[0] = (_Float16)rA[j][0]; h[1] = (_Float16)rA[j][1];
        h[2] = (_Float16)rA[j][2]; h[3] = (_Float16)rA[j][3];
        *(f16x4*)(ABUF(0) + wA[j]) = h;
    }
    #pragma unroll
    for (int j = 0; j < 4; ++j) rA[j] = *(const f32x4*)(aRow[j] + 32);      // A(1)
    { char* d = BBUF(1) + wid * 1024; async16(b0 + 64, d); async16(b1 + 64, d + 4096); }  // B(1)
    asm volatile("s_waitcnt vmcnt(6)" ::: "memory");   // retires B(0); A(1),B(1) in flight
    asm volatile("s_waitcnt lgkmcnt(0)" ::: "memory");
    __builtin_amdgcn_s_barrier();

    for (int kt = 0; kt < nt; ++kt) {
        // (a) cvt + ds_write A(kt+1)
        if (kt + 1 < nt) {
            char* ad = ABUF(kt + 1);
            #pragma unroll
            for (int j = 0; j < 4; ++j) {
                f16x4 h;
                h[0] = (_Float16)rA[j][0]; h[1] = (_Float16)rA[j][1];
                h[2] = (_Float16)rA[j][2]; h[3] = (_Float16)rA[j][3];
                *(f16x4*)(ad + wA[j]) = h;
            }
        }
        // (b,c) issue next-next tile staging
        if (kt + 2 < nt) {
            #pragma unroll
            for (int j = 0; j < 4; ++j) rA[j] = *(const f32x4*)(aRow[j] + (size_t)(kt + 2) * 32);
            char* d = BBUF(kt + 2) + wid * 1024;
            const char* s = b0 + (size_t)(kt + 2) * 64;
            async16(s, d);
            async16(s + (size_t)64 * K * 2, d + 4096);
        }
        // (d) fragment reads
        f16x8 a[4], b[4];
        const char* ab = ABUF(kt);
        const char* bb = BBUF(kt);
        #pragma unroll
        for (int n = 0; n < 4; ++n) b[n] = *(const f16x8*)(bb + boff + n * 1024);
        #pragma unroll
        for (int m = 0; m < 4; ++m) a[m] = *(const f16x8*)(ab + aoff + m * 1024);
        // (e) MFMA
        __builtin_amdgcn_s_setprio(1);
        #pragma unroll
        for (int m = 0; m < 4; ++m)
            #pragma unroll
            for (int n = 0; n < 4; ++n)
                acc[m][n] = __builtin_amdgcn_mfma_f32_16x16x32_f16(a[m], b[n], acc[m][n], 0, 0, 0);
        __builtin_amdgcn_s_setprio(0);
        // (f,g) counted retirement + write visibility + barrier
        if (kt + 2 < nt)      { asm volatile("s_waitcnt vmcnt(6)" ::: "memory"); }
        else if (kt + 1 < nt) { asm volatile("s_waitcnt vmcnt(0)" ::: "memory"); }
        if (kt + 1 < nt) {
            asm volatile("s_waitcnt lgkmcnt(0)" ::: "memory");
            __builtin_amdgcn_s_barrier();
        }
    }

    // ---- fused Ghost BatchNorm + priors epilogue; z written f16 ----
    __syncthreads();
    #pragma unroll
    for (int n = 0; n < 4; ++n) {
        float s1 = 0.f, s2 = 0.f;
        #pragma unroll
        for (int m = 0; m < 4; ++m)
            #pragma unroll
            for (int j = 0; j < 4; ++j) {
                float v = acc[m][n][j];
                s1 += v; s2 += v * v;
            }
        s1 += __shfl_xor(s1, 16); s2 += __shfl_xor(s2, 16);
        s1 += __shfl_xor(s1, 32); s2 += __shfl_xor(s2, 32);
        if (lane < 16) {
            red[wr][wc * 64 + n * 16 + lane][0] = s1;
            red[wr][wc * 64 + n * 16 + lane][1] = s2;
        }
    }
    __syncthreads();

    const int rowb = row0 + wr * 64 + kg * 4;
    #pragma unroll
    for (int n = 0; n < 4; ++n) {
        const int c = wc * 64 + n * 16 + fr;
        float s1 = red[0][c][0] + red[1][c][0];
        float s2 = red[0][c][1] + red[1][c][1];
        float mean = s1 * (1.f / 128.f);
        float var  = s2 * (1.f / 128.f) - mean * mean;
        float rstd = rsqrtf(var + BN_EPS);
        float g = gamma[col0 + c] * rstd;
        float b = beta[col0 + c] - mean * g;
        #pragma unroll
        for (int m = 0; m < 4; ++m)
            #pragma unroll
            for (int j = 0; j < 4; ++j) {
                int r = rowb + m * 16 + j;
                size_t off = (size_t)r * N + col0 + c;
                Zh[off] = (_Float16)((acc[m][n][j] * g + b) * priors[off]);
            }
    }
}

// ---------------- sparsemax: one wave per row (1024), f16 input, exact Michelot ----------------
__device__ __forceinline__ float waveSum(float v) {
    #pragma unroll
    for (int off = 32; off > 0; off >>= 1) v += __shfl_xor(v, off);
    return v;
}

__global__ __launch_bounds__(256)
void sparsemax_kernel(const _Float16* __restrict__ Zh, float* __restrict__ Out) {
    const int lane = threadIdx.x & 63;
    const int wid  = threadIdx.x >> 6;
    const size_t row = (size_t)blockIdx.x * 4 + wid;
    const f16x8* zr = (const f16x8*)(Zh + row * 1024);

    float p[16];
    #pragma unroll
    for (int j = 0; j < 2; ++j) {
        f16x8 v = zr[lane * 2 + j];
        #pragma unroll
        for (int e = 0; e < 8; ++e) p[8 * j + e] = (float)v[e];
    }

    float s = 0.f;
    #pragma unroll
    for (int i = 0; i < 16; ++i) s += p[i];
    s = waveSum(s);

    float kc  = 1024.f;
    float tau = (s - 1.f) * (1.f / 1024.f);
    for (int it = 0; it < 64; ++it) {
        float s2 = 0.f, c2 = 0.f;
        #pragma unroll
        for (int i = 0; i < 16; ++i) {
            if (p[i] > tau) { s2 += p[i]; c2 += 1.f; }
        }
        s2 = waveSum(s2); c2 = waveSum(c2);
        if (c2 == kc) break;        // support stable -> tau exact
        kc = c2;
        tau = (s2 - 1.f) / c2;
    }

    float* outr = Out + row * 1024 + lane * 16;
    #pragma unroll
    for (int j = 0; j < 4; ++j) {
        float4 o;
        o.x = fmaxf(p[4 * j + 0] - tau, 0.f);
        o.y = fmaxf(p[4 * j + 1] - tau, 0.f);
        o.z = fmaxf(p[4 * j + 2] - tau, 0.f);
        o.w = fmaxf(p[4 * j + 3] - tau, 0.f);
        *(float4*)(outr + 4 * j) = o;
    }
}

extern "C" void kernel_launch(void* const* d_in, const int* in_sizes, int n_in,
                              void* d_out, int out_size, void* d_ws, size_t ws_size,
                              hipStream_t stream)
{
    const float* priors = (const float*)d_in[0];
    const float* feat   = (const float*)d_in[1];
    const float* W      = (const float*)d_in[2];
    const float* gamma  = (const float*)d_in[3];
    const float* beta   = (const float*)d_in[4];
    float* out = (float*)d_out;

    const int Nf = in_sizes[3];              // 1024
    const int Kf = in_sizes[2] / Nf;         // 2048
    const int Mr = in_sizes[1] / Kf;         // 32768

    _Float16* Wh = (_Float16*)d_ws;                                   // 4 MB
    _Float16* Zh = (_Float16*)((char*)d_ws + (size_t)Nf * Kf * 2);    // 64 MB

    {
        int n8 = Nf * (Kf / 8);
        cast_f32_f16<<<(n8 + 255) / 256, 256, 0, stream>>>(W, Wh, n8);
    }

    int nblk = (Mr / 128) * (Nf / 128);      // 2048, divisible by 8
    gemm_gbn_kernel<<<nblk, 256, 0, stream>>>(feat, Wh, priors, gamma, beta, Zh, Mr, Nf, Kf);

    sparsemax_kernel<<<Mr / 4, 256, 0, stream>>>(Zh, out);
}

// Round 15
// 284.095 us; speedup vs baseline: 2.2017x; 1.1822x over previous
//
#include <hip/hip_runtime.h>
#include <hip/hip_bf16.h>
#include <cstdint>

typedef __attribute__((ext_vector_type(4))) float f32x4;
typedef _Float16 f16x8 __attribute__((ext_vector_type(8)));
typedef _Float16 f16x4 __attribute__((ext_vector_type(4)));

#define BN_EPS 1e-5f

// ---------------- fp32 -> fp16 cast (only W, 4 MB) ----------------
__global__ __launch_bounds__(256)
void cast_f32_f16(const float* __restrict__ src, _Float16* __restrict__ dst, int n8) {
    int i = blockIdx.x * blockDim.x + threadIdx.x;
    if (i >= n8) return;
    const float4* s4 = (const float4*)src;
    float4 a = s4[2 * (size_t)i];
    float4 b = s4[2 * (size_t)i + 1];
    f16x8 h;
    h[0] = (_Float16)a.x; h[1] = (_Float16)a.y; h[2] = (_Float16)a.z; h[3] = (_Float16)a.w;
    h[4] = (_Float16)b.x; h[5] = (_Float16)b.y; h[6] = (_Float16)b.z; h[7] = (_Float16)b.w;
    *(f16x8*)(dst + 8 * (size_t)i) = h;
}

// async global->LDS, 16B per lane, wave-uniform LDS base (B path)
__device__ __forceinline__ void async16(const char* g, char* l) {
    __builtin_amdgcn_global_load_lds(
        (const __attribute__((address_space(1))) unsigned int*)(uintptr_t)g,
        (__attribute__((address_space(3))) unsigned int*)(uintptr_t)l,
        16, 0, 0);
}

// ====== 256x256, BK=32, 3-buffer; fused A-cast (r14 schedule, proven) at 256² tile ======
// r14's schedule at 128² stalled: A-load issue->consume distance = 1 tile body (~1000cyc)
// < HBM latency (~900cyc, m126). At 256² the body is ~2500cyc -> latency covered.
// A: coalesced fp32 loads (8 rows x 8 lanes = full 128B lines) -> cvt -> ds_write_b64 into
// the measured-0-conflict f16 [256][32]+XOR layout (write pattern proven 0-conflict, r14).
// B: global_load_lds, pre-permuted source (proven r3-r9). Reads = r4/r9 proven pattern.
// FIFO ledger per wave (A=4 reg loads, B=2 asyncs), 1 barrier/tile:
//  (a) cvt+write A(kt+1)  [compiler reg-dep wait = vmcnt(2), leaves B(kt+1)]
//  (b) issue A(kt+2) loads (c) issue B(kt+2) asyncs
//  (d) 12 ds_read frags(kt) (e) 32 MFMA
//  (f) vmcnt(6) retires B(kt+1)   [outstanding: B(kt+1)2 | A(kt+2)4 | B(kt+2)2]
//  (g) lgkmcnt(0) [ds_writes visible] ; barrier
// WAR: (a)@kt writes ABUF((kt+1)%3); its last reads were @kt-2, drained 2 barriers ago.
// Tail: kt=nt-2 -> vmcnt(0); kt=nt-1 -> no stage, no trailing barrier.

#define ABUF(t) (lds + ((t) % 3) * 16384)
#define BBUF(t) (lds + 49152 + ((t) % 3) * 16384)

__device__ __forceinline__ void cvtWrite(char* addr, const f32x4& v) {
    f16x4 h;
    h[0] = (_Float16)v[0]; h[1] = (_Float16)v[1];
    h[2] = (_Float16)v[2]; h[3] = (_Float16)v[3];
    *(f16x4*)addr = h;
}

__global__ __launch_bounds__(512, 2)
void gemm_gbn_kernel(const float* __restrict__ Af,
                     const _Float16* __restrict__ Bw,
                     const float* __restrict__ priors,
                     const float* __restrict__ gamma,
                     const float* __restrict__ beta,
                     _Float16* __restrict__ Zh,
                     int M, int N, int K)
{
    __shared__ __align__(16) char lds[98304];   // A 3x16KB + B 3x16KB

    const int tid  = threadIdx.x;
    const int lane = tid & 63;
    const int wid  = tid >> 6;     // 0..7
    const int wr   = wid >> 2;     // 0..1  (128-row half == one virtual batch)
    const int wc   = wid & 3;      // 0..3  (64-col slice)
    const int fr   = lane & 15;
    const int kg   = lane >> 4;

    // XCD-aware bijective swizzle (512 blocks, %8==0)
    const int bid = blockIdx.x;
    const int swz = (bid & 7) * 64 + (bid >> 3);
    const int row0 = (swz >> 2) * 256;
    const int col0 = (swz & 3) * 256;

    // ---- A fused-cast staging: load j covers row (tid>>3)+j*64, fp32 granule (tid&7) ----
    const float* aBase = Af + (size_t)(row0 + (tid >> 3)) * (size_t)K + (tid & 7) * 4;
    const size_t aRowStep = (size_t)64 * K;    // j stride (64 rows)
    int wA[4];
    {
        const int sub = tid & 7;
        #pragma unroll
        for (int j = 0; j < 4; ++j) {
            const int r = (tid >> 3) + j * 64;
            wA[j] = r * 64 + (((sub >> 1) ^ ((r >> 1) & 3)) * 16) + (sub & 1) * 8;
        }
    }

    // ---- B staging (proven gload_lds path) ----
    const int bperm = ((tid & 3) ^ ((tid >> 3) & 3)) * 16;
    const char* b0 = (const char*)Bw + (size_t)(col0 + (tid >> 2)) * (size_t)K * 2 + bperm;
    const char* b1 = b0 + (size_t)128 * K * 2;
    const int widB = wid * 1024;

    // ---- fragment read offsets ([256][32] f16, 64B rows, measured-0-conflict swizzle) ----
    int aoff = (wr * 128 + fr) * 64 + kg * 16;
    aoff ^= ((aoff >> 7) & 3) << 4;
    int boff = (wc * 64 + fr) * 64 + kg * 16;
    boff ^= ((boff >> 7) & 3) << 4;

    f32x4 acc[8][4];
    #pragma unroll
    for (int m = 0; m < 8; ++m)
        #pragma unroll
        for (int n = 0; n < 4; ++n)
            acc[m][n] = (f32x4)0.0f;

    const int nt = K >> 5;   // 64 K-tiles of 32
    f32x4 rA[4];

    // ---- prologue ----
    #pragma unroll
    for (int j = 0; j < 4; ++j) rA[j] = *(const f32x4*)(aBase + j * aRowStep);      // A(0)
    { char* d = BBUF(0) + widB; async16(b0, d); async16(b1, d + 8192); }            // B(0)
    #pragma unroll
    for (int j = 0; j < 4; ++j) cvtWrite(ABUF(0) + wA[j], rA[j]);                   // write A(0)
    #pragma unroll
    for (int j = 0; j < 4; ++j) rA[j] = *(const f32x4*)(aBase + j * aRowStep + 32); // A(1)
    { char* d = BBUF(1) + widB; async16(b0 + 64, d); async16(b1 + 64, d + 8192); }  // B(1)
    asm volatile("s_waitcnt vmcnt(6)" ::: "memory");    // retires B(0); A(1),B(1) in flight
    asm volatile("s_waitcnt lgkmcnt(0)" ::: "memory");
    __builtin_amdgcn_s_barrier();

    for (int kt = 0; kt < nt; ++kt) {
        // (a) cvt + ds_write A(kt+1)
        if (kt + 1 < nt) {
            char* ad = ABUF(kt + 1);
            #pragma unroll
            for (int j = 0; j < 4; ++j) cvtWrite(ad + wA[j], rA[j]);
        }
        // (b,c) issue tile kt+2 staging
        if (kt + 2 < nt) {
            #pragma unroll
            for (int j = 0; j < 4; ++j)
                rA[j] = *(const f32x4*)(aBase + j * aRowStep + (size_t)(kt + 2) * 32);
            char* d = BBUF(kt + 2) + widB;
            async16(b0 + (size_t)(kt + 2) * 64, d);
            async16(b1 + (size_t)(kt + 2) * 64, d + 8192);
        }
        // (d) fragment reads
        f16x8 a[8], b[4];
        const char* ab = ABUF(kt);
        const char* bb = BBUF(kt);
        #pragma unroll
        for (int n = 0; n < 4; ++n) b[n] = *(const f16x8*)(bb + boff + n * 1024);
        #pragma unroll
        for (int m = 0; m < 8; ++m) a[m] = *(const f16x8*)(ab + aoff + m * 1024);
        // (e) MFMA
        __builtin_amdgcn_s_setprio(1);
        #pragma unroll
        for (int m = 0; m < 8; ++m)
            #pragma unroll
            for (int n = 0; n < 4; ++n)
                acc[m][n] = __builtin_amdgcn_mfma_f32_16x16x32_f16(a[m], b[n], acc[m][n], 0, 0, 0);
        __builtin_amdgcn_s_setprio(0);
        // (f,g) counted retirement + write visibility + barrier
        if (kt + 2 < nt)      { asm volatile("s_waitcnt vmcnt(6)" ::: "memory"); }
        else if (kt + 1 < nt) { asm volatile("s_waitcnt vmcnt(0)" ::: "memory"); }
        if (kt + 1 < nt) {
            asm volatile("s_waitcnt lgkmcnt(0)" ::: "memory");
            __builtin_amdgcn_s_barrier();
        }
    }

    // ---- fused Ghost BatchNorm + priors epilogue (wave-local; z written f16) ----
    #pragma unroll
    for (int n = 0; n < 4; ++n) {
        float s1 = 0.f, s2 = 0.f;
        #pragma unroll
        for (int m = 0; m < 8; ++m)
            #pragma unroll
            for (int j = 0; j < 4; ++j) {
                float v = acc[m][n][j];
                s1 += v; s2 += v * v;
            }
        s1 += __shfl_xor(s1, 16); s2 += __shfl_xor(s2, 16);
        s1 += __shfl_xor(s1, 32); s2 += __shfl_xor(s2, 32);
        float mean = s1 * (1.f / 128.f);
        float var  = s2 * (1.f / 128.f) - mean * mean;
        float rstd = rsqrtf(var + BN_EPS);
        const int c = col0 + wc * 64 + n * 16 + fr;
        float g = gamma[c] * rstd;
        float b = beta[c] - mean * g;
        #pragma unroll
        for (int m = 0; m < 8; ++m)
            #pragma unroll
            for (int j = 0; j < 4; ++j) {
                int r = row0 + wr * 128 + m * 16 + kg * 4 + j;
                size_t off = (size_t)r * N + c;
                Zh[off] = (_Float16)((acc[m][n][j] * g + b) * priors[off]);
            }
    }
}

// ---------------- sparsemax: one wave per row (1024), f16 input, exact Michelot ----------------
__device__ __forceinline__ float waveSum(float v) {
    #pragma unroll
    for (int off = 32; off > 0; off >>= 1) v += __shfl_xor(v, off);
    return v;
}

__global__ __launch_bounds__(256)
void sparsemax_kernel(const _Float16* __restrict__ Zh, float* __restrict__ Out) {
    const int lane = threadIdx.x & 63;
    const int wid  = threadIdx.x >> 6;
    const size_t row = (size_t)blockIdx.x * 4 + wid;
    const f16x8* zr = (const f16x8*)(Zh + row * 1024);

    float p[16];
    #pragma unroll
    for (int j = 0; j < 2; ++j) {
        f16x8 v = zr[lane * 2 + j];
        #pragma unroll
        for (int e = 0; e < 8; ++e) p[8 * j + e] = (float)v[e];
    }

    float s = 0.f;
    #pragma unroll
    for (int i = 0; i < 16; ++i) s += p[i];
    s = waveSum(s);

    float kc  = 1024.f;
    float tau = (s - 1.f) * (1.f / 1024.f);
    for (int it = 0; it < 64; ++it) {
        float s2 = 0.f, c2 = 0.f;
        #pragma unroll
        for (int i = 0; i < 16; ++i) {
            if (p[i] > tau) { s2 += p[i]; c2 += 1.f; }
        }
        s2 = waveSum(s2); c2 = waveSum(c2);
        if (c2 == kc) break;        // support stable -> tau exact
        kc = c2;
        tau = (s2 - 1.f) / c2;
    }

    float* outr = Out + row * 1024 + lane * 16;
    #pragma unroll
    for (int j = 0; j < 4; ++j) {
        float4 o;
        o.x = fmaxf(p[4 * j + 0] - tau, 0.f);
        o.y = fmaxf(p[4 * j + 1] - tau, 0.f);
        o.z = fmaxf(p[4 * j + 2] - tau, 0.f);
        o.w = fmaxf(p[4 * j + 3] - tau, 0.f);
        *(float4*)(outr + 4 * j) = o;
    }
}

extern "C" void kernel_launch(void* const* d_in, const int* in_sizes, int n_in,
                              void* d_out, int out_size, void* d_ws, size_t ws_size,
                              hipStream_t stream)
{
    const float* priors = (const float*)d_in[0];
    const float* feat   = (const float*)d_in[1];
    const float* W      = (const float*)d_in[2];
    const float* gamma  = (const float*)d_in[3];
    const float* beta   = (const float*)d_in[4];
    float* out = (float*)d_out;

    const int Nf = in_sizes[3];              // 1024
    const int Kf = in_sizes[2] / Nf;         // 2048
    const int Mr = in_sizes[1] / Kf;         // 32768

    _Float16* Wh = (_Float16*)d_ws;                                   // 4 MB
    _Float16* Zh = (_Float16*)((char*)d_ws + (size_t)Nf * Kf * 2);    // 64 MB

    {
        int n8 = Nf * (Kf / 8);
        cast_f32_f16<<<(n8 + 255) / 256, 256, 0, stream>>>(W, Wh, n8);
    }

    int nblk = (Mr / 256) * (Nf / 256);      // 512, divisible by 8
    gemm_gbn_kernel<<<nblk, 512, 0, stream>>>(feat, Wh, priors, gamma, beta, Zh, Mr, Nf, Kf);

    sparsemax_kernel<<<Mr / 4, 256, 0, stream>>>(Zh, out);
}

// Round 16
// 276.054 us; speedup vs baseline: 2.2658x; 1.0291x over previous
//
#include <hip/hip_runtime.h>
#include <hip/hip_bf16.h>
#include <cstdint>

typedef __attribute__((ext_vector_type(4))) float f32x4;
typedef _Float16 f16x8 __attribute__((ext_vector_type(8)));
typedef _Float16 f16x4 __attribute__((ext_vector_type(4)));

#define BN_EPS 1e-5f

// ---------------- fp32 -> fp16 cast (only W, 4 MB) ----------------
__global__ __launch_bounds__(256)
void cast_f32_f16(const float* __restrict__ src, _Float16* __restrict__ dst, int n8) {
    int i = blockIdx.x * blockDim.x + threadIdx.x;
    if (i >= n8) return;
    const float4* s4 = (const float4*)src;
    float4 a = s4[2 * (size_t)i];
    float4 b = s4[2 * (size_t)i + 1];
    f16x8 h;
    h[0] = (_Float16)a.x; h[1] = (_Float16)a.y; h[2] = (_Float16)a.z; h[3] = (_Float16)a.w;
    h[4] = (_Float16)b.x; h[5] = (_Float16)b.y; h[6] = (_Float16)b.z; h[7] = (_Float16)b.w;
    *(f16x8*)(dst + 8 * (size_t)i) = h;
}

// async global->LDS, 16B per lane, wave-uniform LDS base (B path)
__device__ __forceinline__ void async16(const char* g, char* l) {
    __builtin_amdgcn_global_load_lds(
        (const __attribute__((address_space(1))) unsigned int*)(uintptr_t)g,
        (__attribute__((address_space(3))) unsigned int*)(uintptr_t)l,
        16, 0, 0);
}

// ====== r15 + DEPTH-2 prefetch: 256x256, BK=32; A regs double-buffered, B 4 LDS bufs ======
// r15's ledger had sub-body issue->consume distances (A: ~0.7 body, B: ~1.0 body) vs ~900cyc
// HBM latency -> per-tile drains at (a) and (f). Depth-2 gives ~2 bodies of cover.
// FIFO ledger per wave (A=4 reg loads, B=2 asyncs), iteration kt:
//   entering: [A(kt+1)4, B(kt+1)2, A(kt+2)4, B(kt+2)2] = 12 outstanding
//   (a) cvt+ds_write A(kt+1) from rA[s]   [compiler waits vmcnt(8) -> retires A(kt+1)]
//   (b) issue A(kt+3) -> rA[s] (slot just freed; s=(kt+1)&1, static via pair-unroll)
//   (c) issue B(kt+3) asyncs -> BBUF((kt+3)%4)    [outstanding 14]
//   (d) 12 ds_read frags(kt)  (e) 32 MFMA (setprio)
//   (f) vmcnt(12) retires B(kt+1)  (g) lgkmcnt(0) [A-writes visible]; barrier
// WAR: ds_write@kt -> ABUF((kt+1)%3), last read @kt-2, drained 2 barriers ago. B async@kt ->
// BBUF((kt+3)%4)=BBUF((kt-1)%4), last read @kt-1, all waves past barrier@kt-1. Safe.
// Tails (nt even): kt=nt-4 steady (stages nt-1); nt-3: no stage, vmcnt(6); nt-2: vmcnt(0);
// nt-1: compute only. LDS = A 3x16KB + B 4x16KB = 112KB (1 block/CU, same as r15).

#define ABUF(t) (lds + ((t) % 3) * 16384)
#define BBUF(t) (lds + 49152 + ((t) % 4) * 16384)

__device__ __forceinline__ void cvtWrite(char* addr, const f32x4& v) {
    f16x4 h;
    h[0] = (_Float16)v[0]; h[1] = (_Float16)v[1];
    h[2] = (_Float16)v[2]; h[3] = (_Float16)v[3];
    *(f16x4*)addr = h;
}

template<int WAITN, bool STAGE, bool WRITEA, bool BAR>
__device__ __forceinline__ void ktile(
    int kt, char* lds, const float* aBase, size_t aRowStep,
    const char* b0, const char* b1, int widB,
    int aoff, int boff, const int (&wA)[4], f32x4 (&rAs)[4],
    f32x4 (&acc)[8][4])
{
    // (a) cvt + ds_write A(kt+1)
    if (WRITEA) {
        char* ad = ABUF(kt + 1);
        #pragma unroll
        for (int j = 0; j < 4; ++j) cvtWrite(ad + wA[j], rAs[j]);
    }
    // (b,c) issue tile kt+3 staging (A into the slot just consumed)
    if (STAGE) {
        #pragma unroll
        for (int j = 0; j < 4; ++j)
            rAs[j] = *(const f32x4*)(aBase + j * aRowStep + (size_t)(kt + 3) * 32);
        char* d = BBUF(kt + 3) + widB;
        async16(b0 + (size_t)(kt + 3) * 64, d);
        async16(b1 + (size_t)(kt + 3) * 64, d + 8192);
    }
    // (d) fragment reads
    f16x8 a[8], b[4];
    const char* ab = ABUF(kt);
    const char* bb = BBUF(kt);
    #pragma unroll
    for (int n = 0; n < 4; ++n) b[n] = *(const f16x8*)(bb + boff + n * 1024);
    #pragma unroll
    for (int m = 0; m < 8; ++m) a[m] = *(const f16x8*)(ab + aoff + m * 1024);
    // (e) MFMA
    __builtin_amdgcn_s_setprio(1);
    #pragma unroll
    for (int m = 0; m < 8; ++m)
        #pragma unroll
        for (int n = 0; n < 4; ++n)
            acc[m][n] = __builtin_amdgcn_mfma_f32_16x16x32_f16(a[m], b[n], acc[m][n], 0, 0, 0);
    __builtin_amdgcn_s_setprio(0);
    // (f,g)
    if (WAITN == 12)     { asm volatile("s_waitcnt vmcnt(12)" ::: "memory"); }
    else if (WAITN == 6) { asm volatile("s_waitcnt vmcnt(6)" ::: "memory"); }
    else if (WAITN == 0) { asm volatile("s_waitcnt vmcnt(0)" ::: "memory"); }
    if (BAR) {
        asm volatile("s_waitcnt lgkmcnt(0)" ::: "memory");
        __builtin_amdgcn_s_barrier();
    }
}

__global__ __launch_bounds__(512, 2)
void gemm_gbn_kernel(const float* __restrict__ Af,
                     const _Float16* __restrict__ Bw,
                     const float* __restrict__ priors,
                     const float* __restrict__ gamma,
                     const float* __restrict__ beta,
                     _Float16* __restrict__ Zh,
                     int M, int N, int K)
{
    __shared__ __align__(16) char lds[114688];   // A 3x16KB + B 4x16KB

    const int tid  = threadIdx.x;
    const int lane = tid & 63;
    const int wid  = tid >> 6;     // 0..7
    const int wr   = wid >> 2;     // 0..1  (128-row half == one virtual batch)
    const int wc   = wid & 3;      // 0..3  (64-col slice)
    const int fr   = lane & 15;
    const int kg   = lane >> 4;

    // XCD-aware bijective swizzle (512 blocks, %8==0)
    const int bid = blockIdx.x;
    const int swz = (bid & 7) * 64 + (bid >> 3);
    const int row0 = (swz >> 2) * 256;
    const int col0 = (swz & 3) * 256;

    // ---- A fused-cast staging: load j covers row (tid>>3)+j*64, fp32 granule (tid&7) ----
    const float* aBase = Af + (size_t)(row0 + (tid >> 3)) * (size_t)K + (tid & 7) * 4;
    const size_t aRowStep = (size_t)64 * K;
    int wA[4];
    {
        const int sub = tid & 7;
        #pragma unroll
        for (int j = 0; j < 4; ++j) {
            const int r = (tid >> 3) + j * 64;
            wA[j] = r * 64 + (((sub >> 1) ^ ((r >> 1) & 3)) * 16) + (sub & 1) * 8;
        }
    }

    // ---- B staging (proven gload_lds path) ----
    const int bperm = ((tid & 3) ^ ((tid >> 3) & 3)) * 16;
    const char* b0 = (const char*)Bw + (size_t)(col0 + (tid >> 2)) * (size_t)K * 2 + bperm;
    const char* b1 = b0 + (size_t)128 * K * 2;
    const int widB = wid * 1024;

    // ---- fragment read offsets ([256][32] f16, 64B rows, measured-0-conflict swizzle) ----
    int aoff = (wr * 128 + fr) * 64 + kg * 16;
    aoff ^= ((aoff >> 7) & 3) << 4;
    int boff = (wc * 64 + fr) * 64 + kg * 16;
    boff ^= ((boff >> 7) & 3) << 4;

    f32x4 acc[8][4];
    #pragma unroll
    for (int m = 0; m < 8; ++m)
        #pragma unroll
        for (int n = 0; n < 4; ++n)
            acc[m][n] = (f32x4)0.0f;

    const int nt = K >> 5;   // 64 K-tiles of 32 (even)
    f32x4 rA0[4], rA1[4];

    // ---- prologue: A(0)->rA0, B(0); A(1)->rA1, B(1); write A(0); A(2)->rA0; B(2) ----
    #pragma unroll
    for (int j = 0; j < 4; ++j) rA0[j] = *(const f32x4*)(aBase + j * aRowStep);
    { char* d = BBUF(0) + widB; async16(b0, d); async16(b1, d + 8192); }
    #pragma unroll
    for (int j = 0; j < 4; ++j) rA1[j] = *(const f32x4*)(aBase + j * aRowStep + 32);
    { char* d = BBUF(1) + widB; async16(b0 + 64, d); async16(b1 + 64, d + 8192); }
    #pragma unroll
    for (int j = 0; j < 4; ++j) cvtWrite(ABUF(0) + wA[j], rA0[j]);   // waits A(0) only
    #pragma unroll
    for (int j = 0; j < 4; ++j) rA0[j] = *(const f32x4*)(aBase + j * aRowStep + 64);
    { char* d = BBUF(2) + widB; async16(b0 + 128, d); async16(b1 + 128, d + 8192); }
    asm volatile("s_waitcnt vmcnt(12)" ::: "memory");   // retires B(0)
    asm volatile("s_waitcnt lgkmcnt(0)" ::: "memory");
    __builtin_amdgcn_s_barrier();

    // ---- main loop: slot s(kt)=(kt+1)&1 -> even kt uses rA1, odd kt uses rA0 ----
    int kt = 0;
    for (; kt + 5 < nt; kt += 2) {
        ktile<12, true, true, true>(kt,     lds, aBase, aRowStep, b0, b1, widB, aoff, boff, wA, rA1, acc);
        ktile<12, true, true, true>(kt + 1, lds, aBase, aRowStep, b0, b1, widB, aoff, boff, wA, rA0, acc);
    }
    // kt == nt-4 (even): steady, stages nt-1
    ktile<12, true,  true,  true >(nt - 4, lds, aBase, aRowStep, b0, b1, widB, aoff, boff, wA, rA1, acc);
    ktile<6,  false, true,  true >(nt - 3, lds, aBase, aRowStep, b0, b1, widB, aoff, boff, wA, rA0, acc);
    ktile<0,  false, true,  true >(nt - 2, lds, aBase, aRowStep, b0, b1, widB, aoff, boff, wA, rA1, acc);
    ktile<-1, false, false, false>(nt - 1, lds, aBase, aRowStep, b0, b1, widB, aoff, boff, wA, rA0, acc);

    // ---- fused Ghost BatchNorm + priors epilogue (wave-local; z written f16) ----
    #pragma unroll
    for (int n = 0; n < 4; ++n) {
        float s1 = 0.f, s2 = 0.f;
        #pragma unroll
        for (int m = 0; m < 8; ++m)
            #pragma unroll
            for (int j = 0; j < 4; ++j) {
                float v = acc[m][n][j];
                s1 += v; s2 += v * v;
            }
        s1 += __shfl_xor(s1, 16); s2 += __shfl_xor(s2, 16);
        s1 += __shfl_xor(s1, 32); s2 += __shfl_xor(s2, 32);
        float mean = s1 * (1.f / 128.f);
        float var  = s2 * (1.f / 128.f) - mean * mean;
        float rstd = rsqrtf(var + BN_EPS);
        const int c = col0 + wc * 64 + n * 16 + fr;
        float g = gamma[c] * rstd;
        float b = beta[c] - mean * g;
        #pragma unroll
        for (int m = 0; m < 8; ++m)
            #pragma unroll
            for (int j = 0; j < 4; ++j) {
                int r = row0 + wr * 128 + m * 16 + kg * 4 + j;
                size_t off = (size_t)r * N + c;
                Zh[off] = (_Float16)((acc[m][n][j] * g + b) * priors[off]);
            }
    }
}

// ---------------- sparsemax: one wave per row (1024), f16 input, exact Michelot ----------------
__device__ __forceinline__ float waveSum(float v) {
    #pragma unroll
    for (int off = 32; off > 0; off >>= 1) v += __shfl_xor(v, off);
    return v;
}

__global__ __launch_bounds__(256)
void sparsemax_kernel(const _Float16* __restrict__ Zh, float* __restrict__ Out) {
    const int lane = threadIdx.x & 63;
    const int wid  = threadIdx.x >> 6;
    const size_t row = (size_t)blockIdx.x * 4 + wid;
    const f16x8* zr = (const f16x8*)(Zh + row * 1024);

    float p[16];
    #pragma unroll
    for (int j = 0; j < 2; ++j) {
        f16x8 v = zr[lane * 2 + j];
        #pragma unroll
        for (int e = 0; e < 8; ++e) p[8 * j + e] = (float)v[e];
    }

    float s = 0.f;
    #pragma unroll
    for (int i = 0; i < 16; ++i) s += p[i];
    s = waveSum(s);

    float kc  = 1024.f;
    float tau = (s - 1.f) * (1.f / 1024.f);
    for (int it = 0; it < 64; ++it) {
        float s2 = 0.f, c2 = 0.f;
        #pragma unroll
        for (int i = 0; i < 16; ++i) {
            if (p[i] > tau) { s2 += p[i]; c2 += 1.f; }
        }
        s2 = waveSum(s2); c2 = waveSum(c2);
        if (c2 == kc) break;        // support stable -> tau exact
        kc = c2;
        tau = (s2 - 1.f) / c2;
    }

    float* outr = Out + row * 1024 + lane * 16;
    #pragma unroll
    for (int j = 0; j < 4; ++j) {
        float4 o;
        o.x = fmaxf(p[4 * j + 0] - tau, 0.f);
        o.y = fmaxf(p[4 * j + 1] - tau, 0.f);
        o.z = fmaxf(p[4 * j + 2] - tau, 0.f);
        o.w = fmaxf(p[4 * j + 3] - tau, 0.f);
        *(float4*)(outr + 4 * j) = o;
    }
}

extern "C" void kernel_launch(void* const* d_in, const int* in_sizes, int n_in,
                              void* d_out, int out_size, void* d_ws, size_t ws_size,
                              hipStream_t stream)
{
    const float* priors = (const float*)d_in[0];
    const float* feat   = (const float*)d_in[1];
    const float* W      = (const float*)d_in[2];
    const float* gamma  = (const float*)d_in[3];
    const float* beta   = (const float*)d_in[4];
    float* out = (float*)d_out;

    const int Nf = in_sizes[3];              // 1024
    const int Kf = in_sizes[2] / Nf;         // 2048
    const int Mr = in_sizes[1] / Kf;         // 32768

    _Float16* Wh = (_Float16*)d_ws;                                   // 4 MB
    _Float16* Zh = (_Float16*)((char*)d_ws + (size_t)Nf * Kf * 2);    // 64 MB

    {
        int n8 = Nf * (Kf / 8);
        cast_f32_f16<<<(n8 + 255) / 256, 256, 0, stream>>>(W, Wh, n8);
    }

    int nblk = (Mr / 256) * (Nf / 256);      // 512, divisible by 8
    gemm_gbn_kernel<<<nblk, 512, 0, stream>>>(feat, Wh, priors, gamma, beta, Zh, Mr, Nf, Kf);

    sparsemax_kernel<<<Mr / 4, 256, 0, stream>>>(Zh, out);
}